// Round 6
// baseline (1175.420 us; speedup 1.0000x reference)
//
#include <hip/hip_runtime.h>

#define BATCH 2
#define SEQ   2048
#define HIDSZ 4096
#define NH    32
#define NKV   8
#define HD    128
#define HALFD 64
#define MROWS (BATCH*SEQ)   // 4096
#define KVDIM (NKV*HD)      // 1024

typedef _Float16 f16;
typedef __attribute__((ext_vector_type(4))) float    fx4;
typedef __attribute__((ext_vector_type(4))) _Float16 half4;
typedef __attribute__((ext_vector_type(8))) _Float16 half8;

__device__ __forceinline__ float ldf(const f16* p)   { return (float)*p; }
__device__ __forceinline__ float ldf(const float* p) { return *p; }
__device__ __forceinline__ void  stf(f16* p, float v)   { *p = (f16)v; }
__device__ __forceinline__ void  stf(float* p, float v) { *p = v; }

// ---------------- MFMA GEMM: C[M,N] = A[M,K] @ B[K,N], row-major ------------
// 128x128 tile, BK=32, 256 threads = 4 waves (2x2 of 64x64), f16 MFMA
// 16x16x32, fp32 accum. A/B converted fp32->f16 during reg-staged LDS write.
// LDS tiles padded to stride 40 f16 (80 B = 5x16B): frag ds_read_b128 hits
// 16B-slot (5*row+qd) mod 8 -> permutation over 8 rows -> 2-way max (free).
// B staged with interleaved n-map so write banks spread (4-way max).
template<typename T> struct avec;
template<> struct avec<float> { using type = fx4; };
template<> struct avec<f16>   { using type = half4; };

__device__ __forceinline__ half4 toh4(fx4 v) {
    half4 h; h[0] = (f16)v[0]; h[1] = (f16)v[1]; h[2] = (f16)v[2]; h[3] = (f16)v[3];
    return h;
}
__device__ __forceinline__ half4 toh4(half4 v) { return v; }

template<typename TA, typename TC>
__global__ __launch_bounds__(256)
void gemm_mfma(const TA* __restrict__ A, const float* __restrict__ B,
               TC* __restrict__ C, int M, int N, int K) {
    __shared__ f16 As[128][40];   // [m][k], pad 32->40
    __shared__ f16 Bs[128][40];   // [n][k], pad 32->40
    const int tid  = threadIdx.x;
    const int wave = tid >> 6, lane = tid & 63;
    const int c    = lane & 15, qd = lane >> 4;
    const int wr   = (wave >> 1) * 64, wc = (wave & 1) * 64;

    // XCD-aware block remap (grid sizes here are multiples of 8 -> bijective)
    const int nwg = gridDim.x * gridDim.y;
    const int lin = blockIdx.y * gridDim.x + blockIdx.x;
    const int swz = (lin & 7) * (nwg >> 3) + (lin >> 3);
    const int bx  = swz % gridDim.x, by = swz / gridDim.x;

    // staging maps:
    //   A thread = rows am+32u (am=tid>>3), k-chunk ak..ak+3  (half4 writes,
    //              row-contiguous -> conflict-free)
    //   B thread = n rows (tid&31)+32u, k-chunk kb..kb+3 (lane-consecutive n
    //              -> coalesced dword loads; write banks 20n%32 -> 4-way max)
    const int am = tid >> 3;
    const int ak = (tid & 7) * 4;
    const int bc = tid & 31;
    const int kb = (tid >> 5) * 4;

    const TA*    Ap = A + (size_t)(by * 128 + am) * K + ak;
    const float* Bp = B + (size_t)kb * N + bx * 128 + bc;

    fx4 acc[4][4];
#pragma unroll
    for (int i = 0; i < 4; i++)
#pragma unroll
        for (int j = 0; j < 4; j++)
#pragma unroll
            for (int r = 0; r < 4; r++) acc[i][j][r] = 0.f;

    using AT = typename avec<TA>::type;
    AT    areg[4];
    float breg[4][4];
#pragma unroll
    for (int u = 0; u < 4; u++) {
        areg[u] = *(const AT*)(Ap + (size_t)u * 32 * K);
#pragma unroll
        for (int kk = 0; kk < 4; kk++)
            breg[u][kk] = Bp[(size_t)kk * N + u * 32];
    }

    for (int k0 = 0; k0 < K; k0 += 32) {
        // ---- regs -> LDS (with f16 convert; B transposed in-thread) ----
#pragma unroll
        for (int u = 0; u < 4; u++)
            *(half4*)&As[am + u * 32][ak] = toh4(areg[u]);
#pragma unroll
        for (int u = 0; u < 4; u++) {
            half4 h;
#pragma unroll
            for (int kk = 0; kk < 4; kk++) h[kk] = (f16)breg[u][kk];
            *(half4*)&Bs[bc + u * 32][kb] = h;
        }
        __syncthreads();
        // ---- prefetch next K-tile (overlaps with MFMA below) ----
        if (k0 + 32 < K) {
#pragma unroll
            for (int u = 0; u < 4; u++) {
                areg[u] = *(const AT*)(Ap + (size_t)u * 32 * K + (k0 + 32));
#pragma unroll
                for (int kk = 0; kk < 4; kk++)
                    breg[u][kk] = Bp[(size_t)(k0 + 32 + kk) * N + u * 32];
            }
        }
        // ---- fragments + 16 MFMAs ----
        half8 af[4], bf[4];
#pragma unroll
        for (int i = 0; i < 4; i++)
            af[i] = *(const half8*)&As[wr + i * 16 + c][qd * 8];
#pragma unroll
        for (int j = 0; j < 4; j++)
            bf[j] = *(const half8*)&Bs[wc + j * 16 + c][qd * 8];
#pragma unroll
        for (int i = 0; i < 4; i++)
#pragma unroll
            for (int j = 0; j < 4; j++)
                acc[i][j] = __builtin_amdgcn_mfma_f32_16x16x32_f16(
                                af[i], bf[j], acc[i][j], 0, 0, 0);
        __syncthreads();
    }

    // C/D layout: row = qd*4+r, col = c
#pragma unroll
    for (int i = 0; i < 4; i++)
#pragma unroll
        for (int j = 0; j < 4; j++)
#pragma unroll
            for (int r = 0; r < 4; r++)
                stf(&C[(size_t)(by * 128 + wr + i * 16 + qd * 4 + r) * N
                       + bx * 128 + wc + j * 16 + c], acc[i][j][r]);
}

// ---------------- RoPE (in place, tensor of shape [MROWS, heads*HD]) --------
template<typename T>
__global__ void rope_kernel(T* __restrict__ t, int heads) {
    int idx = blockIdx.x * blockDim.x + threadIdx.x;
    int i   = idx & (HALFD - 1);
    int r   = idx >> 6;
    int h   = r % heads;
    int row = r / heads;
    int pos = row & (SEQ - 1);
    float inv_freq = expf(-(float)i * (9.210340371976184f / 64.0f));
    float ang = (float)pos * inv_freq;
    float s, c;
    sincosf(ang, &s, &c);
    size_t base = (size_t)row * ((size_t)heads * HD) + (size_t)h * HD;
    float x1 = ldf(&t[base + i]);
    float x2 = ldf(&t[base + i + HALFD]);
    stf(&t[base + i],         x1 * c - x2 * s);
    stf(&t[base + i + HALFD], x2 * c + x1 * s);
}

// ---------------- V transpose: v[B*SEQ][KVDIM] -> vt[B][NKV][HD][SEQ] -------
__global__ __launch_bounds__(256)
void transpose_v_kernel(const f16* __restrict__ v, f16* __restrict__ vt) {
    __shared__ short tile[32][33];
    int ts = blockIdx.x * 32;          // seq tile
    int td = blockIdx.y * 32;          // d tile within head
    int bk = blockIdx.z;               // b*NKV + kvh
    int b = bk >> 3, kvh = bk & 7;
    int tx = threadIdx.x & 31, ty = threadIdx.x >> 5;
    const short* vp = (const short*)v;
    short* vtp = (short*)vt;
#pragma unroll
    for (int i = 0; i < 4; i++) {
        int s = ts + ty + i * 8;
        tile[ty + i * 8][tx] = vp[(size_t)(b * SEQ + s) * KVDIM + kvh * HD + td + tx];
    }
    __syncthreads();
#pragma unroll
    for (int i = 0; i < 4; i++) {
        int d = td + ty + i * 8;
        vtp[((size_t)(b * NKV + kvh) * HD + d) * SEQ + ts + tx] = tile[tx][ty + i * 8];
    }
}

// ---------------- Flash attention --------------------------------------------
// Block = (b, h, q-tile PAIR {bx, 31-bx}) -> every block does exactly 33
// KV-iterations (load balance). 4 waves; wave w owns q rows [q0+16w .. +15].
// K[64][128] and V^T[128][64] staged cooperatively in LDS per KV tile,
// XOR-swizzled (elem ^= (row&7)<<3) for conflict-free ds_read_b128.
// Async-stage split: next tile's global loads issued at iter top (regs),
// ds_write after post-PV barrier. P round-trip is wave-local (no barrier).
__global__ __launch_bounds__(256)
void flash_attn_kernel(const f16* __restrict__ q, const f16* __restrict__ k,
                       const f16* __restrict__ vt, f16* __restrict__ ao) {
    const int NT = SEQ / 64;               // 32 q-tiles
    int h = blockIdx.y, b = blockIdx.z;
    int kvh = h >> 2;
    int tid = threadIdx.x;
    int wave = tid >> 6, lane = tid & 63;
    int col = lane & 15, quad = lane >> 4;

    __shared__ f16 Ks[64 * 128];   // [seqrow][d ^ swz]
    __shared__ f16 Vs[128 * 64];   // [d][seq ^ swz]
    __shared__ f16 Ps[4 * 16 * 64];// per-wave [qrow][kcol ^ swz]

    const f16* kg0 = k  + (size_t)(b * SEQ) * KVDIM + kvh * HD;
    const f16* vg0 = vt + ((size_t)(b * NKV + kvh) * HD) * SEQ;
    const float scale = 0.08838834764831845f;   // 1/sqrt(128)

#pragma unroll 1
    for (int hf = 0; hf < 2; ++hf) {
        const int qv  = hf ? (NT - 1 - (int)blockIdx.x) : (int)blockIdx.x;
        const int q0  = qv * 64;
        const int nkv = qv + 1;

        // Q frags: qf[ks] = Q[q0+16w+col][h*HD + ks*32 + quad*8 .. +7]
        half8 qf[4];
        {
            const f16* qbase = q +
                (size_t)(b * SEQ + q0 + wave * 16 + col) * HIDSZ + h * HD + quad * 8;
#pragma unroll
            for (int ks = 0; ks < 4; ks++)
                qf[ks] = *(const half8*)(qbase + ks * 32);
        }

        float m_i[4], l_i[4];
#pragma unroll
        for (int r = 0; r < 4; r++) { m_i[r] = -1e30f; l_i[r] = 0.f; }
        fx4 O[8];
#pragma unroll
        for (int n = 0; n < 8; n++)
#pragma unroll
            for (int r = 0; r < 4; r++) O[n][r] = 0.f;

        // K tile: 64 rows x 128 d  = 1024 half8 -> 4 iters x 256 thr
        // V tile: 128 rows x 64 s  = 1024 half8 -> 4 iters x 256 thr
        half8 kreg[4], vreg[4];
        // ---- prologue: stage KV tile j0=0 ----
#pragma unroll
        for (int i = 0; i < 4; i++) {
            int c2 = tid + i * 256, row = c2 >> 4, d0 = (c2 & 15) * 8;
            kreg[i] = *(const half8*)(kg0 + (size_t)row * KVDIM + d0);
        }
#pragma unroll
        for (int i = 0; i < 4; i++) {
            int c2 = tid + i * 256, row = c2 >> 3, s0 = (c2 & 7) * 8;
            vreg[i] = *(const half8*)(vg0 + (size_t)row * SEQ + s0);
        }
        __syncthreads();   // previous tile's readers done before overwrite
#pragma unroll
        for (int i = 0; i < 4; i++) {
            int c2 = tid + i * 256, row = c2 >> 4, d0 = (c2 & 15) * 8;
            *(half8*)&Ks[row * 128 + (d0 ^ ((row & 7) << 3))] = kreg[i];
        }
#pragma unroll
        for (int i = 0; i < 4; i++) {
            int c2 = tid + i * 256, row = c2 >> 3, s0 = (c2 & 7) * 8;
            *(half8*)&Vs[row * 64 + (s0 ^ ((row & 7) << 3))] = vreg[i];
        }
        __syncthreads();

#pragma unroll 1
        for (int t = 0; t < nkv; ++t) {
            const int j0  = t * 64;
            const bool pre = (t + 1 < nkv);
            // ---- issue next tile's global loads (latency hides under compute)
            if (pre) {
                const int jn = j0 + 64;
#pragma unroll
                for (int i = 0; i < 4; i++) {
                    int c2 = tid + i * 256, row = c2 >> 4, d0 = (c2 & 15) * 8;
                    kreg[i] = *(const half8*)(kg0 + (size_t)(jn + row) * KVDIM + d0);
                }
#pragma unroll
                for (int i = 0; i < 4; i++) {
                    int c2 = tid + i * 256, row = c2 >> 3, s0 = (c2 & 7) * 8;
                    vreg[i] = *(const half8*)(vg0 + (size_t)row * SEQ + jn + s0);
                }
            }
            // ---- S[16 x 64] = Q Kt from LDS ----
            fx4 S[4];
#pragma unroll
            for (int nt = 0; nt < 4; nt++) {
                fx4 acc;
#pragma unroll
                for (int r = 0; r < 4; r++) acc[r] = 0.f;
                const int row = nt * 16 + col;
#pragma unroll
                for (int ks = 0; ks < 4; ks++) {
                    half8 kf = *(const half8*)&Ks[row * 128 +
                                   ((ks * 32 + quad * 8) ^ ((row & 7) << 3))];
                    acc = __builtin_amdgcn_mfma_f32_16x16x32_f16(qf[ks], kf, acc, 0, 0, 0);
                }
#pragma unroll
                for (int r = 0; r < 4; r++) S[nt][r] = acc[r] * scale;
            }
            // ---- causal mask (diagonal tile only) ----
            if (j0 == q0) {
                int rowb = wave * 16 + quad * 4;
#pragma unroll
                for (int nt = 0; nt < 4; nt++)
#pragma unroll
                    for (int r = 0; r < 4; r++)
                        if (nt * 16 + col > rowb + r) S[nt][r] = -1e30f;
            }
            // ---- online softmax ----
            float mn[4], alpha[4];
#pragma unroll
            for (int r = 0; r < 4; r++) {
                float mx = fmaxf(fmaxf(S[0][r], S[1][r]), fmaxf(S[2][r], S[3][r]));
#pragma unroll
                for (int d = 8; d >= 1; d >>= 1) mx = fmaxf(mx, __shfl_xor(mx, d, 64));
                mn[r] = fmaxf(m_i[r], mx);
                alpha[r] = __expf(m_i[r] - mn[r]);
                m_i[r] = mn[r];
            }
#pragma unroll
            for (int nt = 0; nt < 4; nt++)
#pragma unroll
                for (int r = 0; r < 4; r++) S[nt][r] = __expf(S[nt][r] - mn[r]);
#pragma unroll
            for (int r = 0; r < 4; r++) {
                float s = (S[0][r] + S[1][r]) + (S[2][r] + S[3][r]);
#pragma unroll
                for (int d = 8; d >= 1; d >>= 1) s += __shfl_xor(s, d, 64);
                l_i[r] = l_i[r] * alpha[r] + s;
            }
#pragma unroll
            for (int n = 0; n < 8; n++)
#pragma unroll
                for (int r = 0; r < 4; r++) O[n][r] *= alpha[r];
            // ---- P: C-layout regs -> LDS -> A-layout frags (wave-local) ----
#pragma unroll
            for (int nt = 0; nt < 4; nt++)
#pragma unroll
                for (int r = 0; r < 4; r++) {
                    int prow = quad * 4 + r;
                    Ps[wave * 1024 + prow * 64 +
                       ((nt * 16 + col) ^ ((prow & 7) << 3))] = (f16)S[nt][r];
                }
            half8 pf[2];
#pragma unroll
            for (int ks2 = 0; ks2 < 2; ks2++)
                pf[ks2] = *(const half8*)&Ps[wave * 1024 + col * 64 +
                              ((ks2 * 32 + quad * 8) ^ ((col & 7) << 3))];
            // ---- O += P V from LDS (8 d-tiles of 16) ----
#pragma unroll
            for (int n = 0; n < 8; n++) {
                const int row = n * 16 + col;
#pragma unroll
                for (int ks2 = 0; ks2 < 2; ks2++) {
                    half8 vf = *(const half8*)&Vs[row * 64 +
                                   ((ks2 * 32 + quad * 8) ^ ((row & 7) << 3))];
                    O[n] = __builtin_amdgcn_mfma_f32_16x16x32_f16(pf[ks2], vf, O[n], 0, 0, 0);
                }
            }
            // ---- write-late: commit prefetched tile to LDS ----
            if (pre) {
                __syncthreads();   // all waves done reading Ks/Vs
#pragma unroll
                for (int i = 0; i < 4; i++) {
                    int c2 = tid + i * 256, row = c2 >> 4, d0 = (c2 & 15) * 8;
                    *(half8*)&Ks[row * 128 + (d0 ^ ((row & 7) << 3))] = kreg[i];
                }
#pragma unroll
                for (int i = 0; i < 4; i++) {
                    int c2 = tid + i * 256, row = c2 >> 3, s0 = (c2 & 7) * 8;
                    *(half8*)&Vs[row * 64 + (s0 ^ ((row & 7) << 3))] = vreg[i];
                }
                __syncthreads();
            }
        }

        // ---- epilogue: normalize, store (C layout) ----
#pragma unroll
        for (int r = 0; r < 4; r++) l_i[r] = 1.f / l_i[r];
        int orow = q0 + wave * 16 + quad * 4;
#pragma unroll
        for (int n = 0; n < 8; n++)
#pragma unroll
            for (int r = 0; r < 4; r++)
                ao[(size_t)(b * SEQ + orow + r) * HIDSZ + h * HD + n * 16 + col] =
                    (f16)(O[n][r] * l_i[r]);
    }
}

// ---------------------------------------------------------------------------
extern "C" void kernel_launch(void* const* d_in, const int* in_sizes, int n_in,
                              void* d_out, int out_size, void* d_ws, size_t ws_size,
                              hipStream_t stream) {
    const float* x  = (const float*)d_in[0];
    const float* wq = (const float*)d_in[1];
    const float* wk = (const float*)d_in[2];
    const float* wv = (const float*)d_in[3];
    const float* wo = (const float*)d_in[4];
    float* out = (float*)d_out;

    // ws: q 32MB | k 8MB | v 8MB | ao 32MB | vt 8MB  = 88MB f16
    f16* q  = (f16*)d_ws;                              // [4096][4096]
    f16* k  = q + (size_t)MROWS * HIDSZ;               // [4096][1024]
    f16* v  = k + (size_t)MROWS * KVDIM;               // [4096][1024]
    f16* ao = v + (size_t)MROWS * KVDIM;               // [4096][4096]
    f16* vt = ao + (size_t)MROWS * HIDSZ;              // [2][8][128][2048]

    gemm_mfma<float, f16><<<dim3(HIDSZ / 128, MROWS / 128), 256, 0, stream>>>(
        x, wq, q, MROWS, HIDSZ, HIDSZ);
    gemm_mfma<float, f16><<<dim3(KVDIM / 128, MROWS / 128), 256, 0, stream>>>(
        x, wk, k, MROWS, KVDIM, HIDSZ);
    gemm_mfma<float, f16><<<dim3(KVDIM / 128, MROWS / 128), 256, 0, stream>>>(
        x, wv, v, MROWS, KVDIM, HIDSZ);

    rope_kernel<f16><<<(MROWS * NH * HALFD) / 256, 256, 0, stream>>>(q, NH);
    rope_kernel<f16><<<(MROWS * NKV * HALFD) / 256, 256, 0, stream>>>(k, NKV);

    transpose_v_kernel<<<dim3(SEQ / 32, HD / 32, BATCH * NKV), 256, 0, stream>>>(v, vt);

    flash_attn_kernel<<<dim3(SEQ / 128, NH, BATCH), 256, 0, stream>>>(q, k, vt, ao);

    gemm_mfma<f16, float><<<dim3(HIDSZ / 128, MROWS / 128), 256, 0, stream>>>(
        ao, wo, out, MROWS, HIDSZ, HIDSZ);
}

// Round 7
// 1104.215 us; speedup vs baseline: 1.0645x; 1.0645x over previous
//
#include <hip/hip_runtime.h>

#define BATCH 2
#define SEQ   2048
#define HIDSZ 4096
#define NH    32
#define NKV   8
#define HD    128
#define HALFD 64
#define MROWS (BATCH*SEQ)   // 4096
#define KVDIM (NKV*HD)      // 1024

typedef _Float16 f16;
typedef __attribute__((ext_vector_type(2))) _Float16 half2v;
typedef __attribute__((ext_vector_type(4))) float    fx4;
typedef __attribute__((ext_vector_type(4))) _Float16 half4;
typedef __attribute__((ext_vector_type(8))) _Float16 half8;

__device__ __forceinline__ float ldf(const f16* p)   { return (float)*p; }
__device__ __forceinline__ float ldf(const float* p) { return *p; }
__device__ __forceinline__ void  stf(f16* p, float v)   { *p = (f16)v; }
__device__ __forceinline__ void  stf(float* p, float v) { *p = v; }

__device__ __forceinline__ void async_ld16(const void* g, void* l) {
    __builtin_amdgcn_global_load_lds(
        (const __attribute__((address_space(1))) void*)g,
        (__attribute__((address_space(3))) void*)l,
        16, 0, 0);
}

// ---- weight transpose+convert: w f32 [K][N] -> wt f16 [N][K] ---------------
__global__ __launch_bounds__(256)
void wtrans_kernel(const float* __restrict__ w, f16* __restrict__ wt,
                   int K, int N) {
    __shared__ float tile[32][33];
    int tn = blockIdx.x * 32;
    int tk = blockIdx.y * 32;
    int tx = threadIdx.x & 31, ty = threadIdx.x >> 5;
#pragma unroll
    for (int i = 0; i < 4; i++)
        tile[ty + i * 8][tx] = w[(size_t)(tk + ty + i * 8) * N + tn + tx];
    __syncthreads();
    int nl0 = threadIdx.x >> 4;        // 0..15
    int kp  = (threadIdx.x & 15) * 2;  // 0,2,..30
#pragma unroll
    for (int p = 0; p < 2; p++) {
        int nl = p * 16 + nl0;
        half2v h2;
        h2[0] = (f16)tile[kp][nl];
        h2[1] = (f16)tile[kp + 1][nl];
        *(half2v*)&wt[(size_t)(tn + nl) * K + tk + kp] = h2;
    }
}

// ---------------- MFMA GEMM: C[M,N] = A[M,K] @ BT[N,K]^T --------------------
// A row-major [M][K] (f32 or f16), BT row-major f16 [N][K] (k-contiguous).
// 128x128 tile, BK=32, 4 waves (2x2 of 64x64), f16 MFMA 16x16x32, fp32 acc.
// A: reg-staged into padded LDS [128][40] (b128 frag reads at bank floor).
// B: global_load_lds width-16 direct into linear LDS [128][32], dbuf;
//    XOR read-swizzle slot = qd ^ ((n>>1)&3), inverse pre-applied to the
//    per-lane global source (both-sides swizzle) -> conflict-free b128 reads.
template<typename T> struct avec;
template<> struct avec<float> { using type = fx4; };
template<> struct avec<f16>   { using type = half4; };

__device__ __forceinline__ half4 toh4(fx4 v) {
    half4 h; h[0] = (f16)v[0]; h[1] = (f16)v[1]; h[2] = (f16)v[2]; h[3] = (f16)v[3];
    return h;
}
__device__ __forceinline__ half4 toh4(half4 v) { return v; }

template<typename TA, typename TC>
__global__ __launch_bounds__(256)
void gemm_bt(const TA* __restrict__ A, const f16* __restrict__ BT,
             TC* __restrict__ C, int M, int N, int K) {
    __shared__ f16 As[128][40];
    __shared__ f16 Bs[2][128 * 32];
    const int tid  = threadIdx.x;
    const int wave = tid >> 6, lane = tid & 63;
    const int c    = lane & 15, qd = lane >> 4;
    const int wr   = (wave >> 1) * 64, wc = (wave & 1) * 64;
    const int bx = blockIdx.x, by = blockIdx.y;

    // A staging: rows am+32u, k ak..ak+3
    const int am = tid >> 3;
    const int ak = (tid & 7) * 4;
    const TA* Ap = A + (size_t)(by * 128 + am) * K + ak;

    // B gload map: lane -> row bn (+64 for pass 1), slot = lane&3,
    // source k-chunk kc = slot ^ ((bn>>1)&3)  (same for both passes: +64 rows
    // doesn't change (n>>1)&3).
    const int bn = wave * 16 + (lane >> 2);
    const int kc = (lane & 3) ^ ((bn >> 1) & 3);
    const f16* Bp0 = BT + (size_t)(bx * 128 + bn) * K + kc * 8;
    const f16* Bp1 = BT + (size_t)(bx * 128 + bn + 64) * K + kc * 8;
    // wave-uniform LDS dest bases (lane*16B appended by HW)
    f16* ldsB0 = &Bs[0][wave * 512];

    fx4 acc[4][4];
#pragma unroll
    for (int i = 0; i < 4; i++)
#pragma unroll
        for (int j = 0; j < 4; j++)
#pragma unroll
            for (int r = 0; r < 4; r++) acc[i][j][r] = 0.f;

    using AT = typename avec<TA>::type;
    AT areg[4];
#pragma unroll
    for (int u = 0; u < 4; u++)
        areg[u] = *(const AT*)(Ap + (size_t)u * 32 * K);

    // prologue: issue B tile 0 into buf 0
    async_ld16(Bp0, ldsB0);
    async_ld16(Bp1, ldsB0 + 2048);

    int cur = 0;
    for (int k0 = 0; k0 < K; k0 += 32) {
        // ---- A regs -> padded LDS (with f16 convert) ----
#pragma unroll
        for (int u = 0; u < 4; u++)
            *(half4*)&As[am + u * 32][ak] = toh4(areg[u]);
        __syncthreads();   // As visible; Bs[cur] gloads drained (vmcnt)
        const bool pre = (k0 + 32) < K;
        if (pre) {
#pragma unroll
            for (int u = 0; u < 4; u++)
                areg[u] = *(const AT*)(Ap + (size_t)u * 32 * K + (k0 + 32));
            f16* dst = &Bs[cur ^ 1][wave * 512];
            async_ld16(Bp0 + (k0 + 32), dst);
            async_ld16(Bp1 + (k0 + 32), dst + 2048);
        }
        // ---- fragments + 16 MFMAs ----
        half8 af[4], bf[4];
#pragma unroll
        for (int i = 0; i < 4; i++)
            af[i] = *(const half8*)&As[wr + i * 16 + c][qd * 8];
#pragma unroll
        for (int j = 0; j < 4; j++) {
            const int n = wc + j * 16 + c;
            bf[j] = *(const half8*)&Bs[cur][n * 32 + ((qd ^ ((n >> 1) & 3)) * 8)];
        }
#pragma unroll
        for (int i = 0; i < 4; i++)
#pragma unroll
            for (int j = 0; j < 4; j++)
                acc[i][j] = __builtin_amdgcn_mfma_f32_16x16x32_f16(
                                af[i], bf[j], acc[i][j], 0, 0, 0);
        __syncthreads();   // all waves done with As & Bs[cur]; next-buf drained
        cur ^= 1;
    }

    // C/D layout: row = qd*4+r, col = c
#pragma unroll
    for (int i = 0; i < 4; i++)
#pragma unroll
        for (int j = 0; j < 4; j++)
#pragma unroll
            for (int r = 0; r < 4; r++)
                stf(&C[(size_t)(by * 128 + wr + i * 16 + qd * 4 + r) * N
                       + bx * 128 + wc + j * 16 + c], acc[i][j][r]);
}

// ---------------- RoPE (in place, tensor of shape [MROWS, heads*HD]) --------
template<typename T>
__global__ void rope_kernel(T* __restrict__ t, int heads) {
    int idx = blockIdx.x * blockDim.x + threadIdx.x;
    int i   = idx & (HALFD - 1);
    int r   = idx >> 6;
    int h   = r % heads;
    int row = r / heads;
    int pos = row & (SEQ - 1);
    float inv_freq = expf(-(float)i * (9.210340371976184f / 64.0f));
    float ang = (float)pos * inv_freq;
    float s, c;
    sincosf(ang, &s, &c);
    size_t base = (size_t)row * ((size_t)heads * HD) + (size_t)h * HD;
    float x1 = ldf(&t[base + i]);
    float x2 = ldf(&t[base + i + HALFD]);
    stf(&t[base + i],         x1 * c - x2 * s);
    stf(&t[base + i + HALFD], x2 * c + x1 * s);
}

// ---------------- V transpose: v[B*SEQ][KVDIM] -> vt[B][NKV][HD][SEQ] -------
__global__ __launch_bounds__(256)
void transpose_v_kernel(const f16* __restrict__ v, f16* __restrict__ vt) {
    __shared__ short tile[32][33];
    int ts = blockIdx.x * 32;          // seq tile
    int td = blockIdx.y * 32;          // d tile within head
    int bk = blockIdx.z;               // b*NKV + kvh
    int b = bk >> 3, kvh = bk & 7;
    int tx = threadIdx.x & 31, ty = threadIdx.x >> 5;
    const short* vp = (const short*)v;
    short* vtp = (short*)vt;
#pragma unroll
    for (int i = 0; i < 4; i++) {
        int s = ts + ty + i * 8;
        tile[ty + i * 8][tx] = vp[(size_t)(b * SEQ + s) * KVDIM + kvh * HD + td + tx];
    }
    __syncthreads();
#pragma unroll
    for (int i = 0; i < 4; i++) {
        int d = td + ty + i * 8;
        vtp[((size_t)(b * NKV + kvh) * HD + d) * SEQ + ts + tx] = tile[tx][ty + i * 8];
    }
}

// ---------------- Flash attention --------------------------------------------
// Block = (b, h, q-tile PAIR {bx, 31-bx}) -> every block does exactly 33
// KV-iterations (load balance). 4 waves; wave w owns q rows [q0+16w .. +15].
// K/V^T staged cooperatively in LDS, XOR-swizzled; async-stage split.
__global__ __launch_bounds__(256)
void flash_attn_kernel(const f16* __restrict__ q, const f16* __restrict__ k,
                       const f16* __restrict__ vt, f16* __restrict__ ao) {
    const int NT = SEQ / 64;               // 32 q-tiles
    int h = blockIdx.y, b = blockIdx.z;
    int kvh = h >> 2;
    int tid = threadIdx.x;
    int wave = tid >> 6, lane = tid & 63;
    int col = lane & 15, quad = lane >> 4;

    __shared__ f16 Ks[64 * 128];   // [seqrow][d ^ swz]
    __shared__ f16 Vs[128 * 64];   // [d][seq ^ swz]
    __shared__ f16 Ps[4 * 16 * 64];// per-wave [qrow][kcol ^ swz]

    const f16* kg0 = k  + (size_t)(b * SEQ) * KVDIM + kvh * HD;
    const f16* vg0 = vt + ((size_t)(b * NKV + kvh) * HD) * SEQ;
    const float scale = 0.08838834764831845f;   // 1/sqrt(128)

#pragma unroll 1
    for (int hf = 0; hf < 2; ++hf) {
        const int qv  = hf ? (NT - 1 - (int)blockIdx.x) : (int)blockIdx.x;
        const int q0  = qv * 64;
        const int nkv = qv + 1;

        half8 qf[4];
        {
            const f16* qbase = q +
                (size_t)(b * SEQ + q0 + wave * 16 + col) * HIDSZ + h * HD + quad * 8;
#pragma unroll
            for (int ks = 0; ks < 4; ks++)
                qf[ks] = *(const half8*)(qbase + ks * 32);
        }

        float m_i[4], l_i[4];
#pragma unroll
        for (int r = 0; r < 4; r++) { m_i[r] = -1e30f; l_i[r] = 0.f; }
        fx4 O[8];
#pragma unroll
        for (int n = 0; n < 8; n++)
#pragma unroll
            for (int r = 0; r < 4; r++) O[n][r] = 0.f;

        half8 kreg[4], vreg[4];
#pragma unroll
        for (int i = 0; i < 4; i++) {
            int c2 = tid + i * 256, row = c2 >> 4, d0 = (c2 & 15) * 8;
            kreg[i] = *(const half8*)(kg0 + (size_t)row * KVDIM + d0);
        }
#pragma unroll
        for (int i = 0; i < 4; i++) {
            int c2 = tid + i * 256, row = c2 >> 3, s0 = (c2 & 7) * 8;
            vreg[i] = *(const half8*)(vg0 + (size_t)row * SEQ + s0);
        }
        __syncthreads();
#pragma unroll
        for (int i = 0; i < 4; i++) {
            int c2 = tid + i * 256, row = c2 >> 4, d0 = (c2 & 15) * 8;
            *(half8*)&Ks[row * 128 + (d0 ^ ((row & 7) << 3))] = kreg[i];
        }
#pragma unroll
        for (int i = 0; i < 4; i++) {
            int c2 = tid + i * 256, row = c2 >> 3, s0 = (c2 & 7) * 8;
            *(half8*)&Vs[row * 64 + (s0 ^ ((row & 7) << 3))] = vreg[i];
        }
        __syncthreads();

#pragma unroll 1
        for (int t = 0; t < nkv; ++t) {
            const int j0  = t * 64;
            const bool pre = (t + 1 < nkv);
            if (pre) {
                const int jn = j0 + 64;
#pragma unroll
                for (int i = 0; i < 4; i++) {
                    int c2 = tid + i * 256, row = c2 >> 4, d0 = (c2 & 15) * 8;
                    kreg[i] = *(const half8*)(kg0 + (size_t)(jn + row) * KVDIM + d0);
                }
#pragma unroll
                for (int i = 0; i < 4; i++) {
                    int c2 = tid + i * 256, row = c2 >> 3, s0 = (c2 & 7) * 8;
                    vreg[i] = *(const half8*)(vg0 + (size_t)row * SEQ + jn + s0);
                }
            }
            fx4 S[4];
#pragma unroll
            for (int nt = 0; nt < 4; nt++) {
                fx4 acc2;
#pragma unroll
                for (int r = 0; r < 4; r++) acc2[r] = 0.f;
                const int row = nt * 16 + col;
#pragma unroll
                for (int ks = 0; ks < 4; ks++) {
                    half8 kf = *(const half8*)&Ks[row * 128 +
                                   ((ks * 32 + quad * 8) ^ ((row & 7) << 3))];
                    acc2 = __builtin_amdgcn_mfma_f32_16x16x32_f16(qf[ks], kf, acc2, 0, 0, 0);
                }
#pragma unroll
                for (int r = 0; r < 4; r++) S[nt][r] = acc2[r] * scale;
            }
            if (j0 == q0) {
                int rowb = wave * 16 + quad * 4;
#pragma unroll
                for (int nt = 0; nt < 4; nt++)
#pragma unroll
                    for (int r = 0; r < 4; r++)
                        if (nt * 16 + col > rowb + r) S[nt][r] = -1e30f;
            }
            float mn[4], alpha[4];
#pragma unroll
            for (int r = 0; r < 4; r++) {
                float mx = fmaxf(fmaxf(S[0][r], S[1][r]), fmaxf(S[2][r], S[3][r]));
#pragma unroll
                for (int d = 8; d >= 1; d >>= 1) mx = fmaxf(mx, __shfl_xor(mx, d, 64));
                mn[r] = fmaxf(m_i[r], mx);
                alpha[r] = __expf(m_i[r] - mn[r]);
                m_i[r] = mn[r];
            }
#pragma unroll
            for (int nt = 0; nt < 4; nt++)
#pragma unroll
                for (int r = 0; r < 4; r++) S[nt][r] = __expf(S[nt][r] - mn[r]);
#pragma unroll
            for (int r = 0; r < 4; r++) {
                float s = (S[0][r] + S[1][r]) + (S[2][r] + S[3][r]);
#pragma unroll
                for (int d = 8; d >= 1; d >>= 1) s += __shfl_xor(s, d, 64);
                l_i[r] = l_i[r] * alpha[r] + s;
            }
#pragma unroll
            for (int n = 0; n < 8; n++)
#pragma unroll
                for (int r = 0; r < 4; r++) O[n][r] *= alpha[r];
#pragma unroll
            for (int nt = 0; nt < 4; nt++)
#pragma unroll
                for (int r = 0; r < 4; r++) {
                    int prow = quad * 4 + r;
                    Ps[wave * 1024 + prow * 64 +
                       ((nt * 16 + col) ^ ((prow & 7) << 3))] = (f16)S[nt][r];
                }
            half8 pf[2];
#pragma unroll
            for (int ks2 = 0; ks2 < 2; ks2++)
                pf[ks2] = *(const half8*)&Ps[wave * 1024 + col * 64 +
                              ((ks2 * 32 + quad * 8) ^ ((col & 7) << 3))];
#pragma unroll
            for (int n = 0; n < 8; n++) {
                const int row = n * 16 + col;
#pragma unroll
                for (int ks2 = 0; ks2 < 2; ks2++) {
                    half8 vf = *(const half8*)&Vs[row * 64 +
                                   ((ks2 * 32 + quad * 8) ^ ((row & 7) << 3))];
                    O[n] = __builtin_amdgcn_mfma_f32_16x16x32_f16(pf[ks2], vf, O[n], 0, 0, 0);
                }
            }
            if (pre) {
                __syncthreads();
#pragma unroll
                for (int i = 0; i < 4; i++) {
                    int c2 = tid + i * 256, row = c2 >> 4, d0 = (c2 & 15) * 8;
                    *(half8*)&Ks[row * 128 + (d0 ^ ((row & 7) << 3))] = kreg[i];
                }
#pragma unroll
                for (int i = 0; i < 4; i++) {
                    int c2 = tid + i * 256, row = c2 >> 3, s0 = (c2 & 7) * 8;
                    *(half8*)&Vs[row * 64 + (s0 ^ ((row & 7) << 3))] = vreg[i];
                }
                __syncthreads();
            }
        }

#pragma unroll
        for (int r = 0; r < 4; r++) l_i[r] = 1.f / l_i[r];
        int orow = q0 + wave * 16 + quad * 4;
#pragma unroll
        for (int n = 0; n < 8; n++)
#pragma unroll
            for (int r = 0; r < 4; r++)
                ao[(size_t)(b * SEQ + orow + r) * HIDSZ + h * HD + n * 16 + col] =
                    (f16)(O[n][r] * l_i[r]);
    }
}

// ---------------------------------------------------------------------------
extern "C" void kernel_launch(void* const* d_in, const int* in_sizes, int n_in,
                              void* d_out, int out_size, void* d_ws, size_t ws_size,
                              hipStream_t stream) {
    const float* x  = (const float*)d_in[0];
    const float* wq = (const float*)d_in[1];
    const float* wk = (const float*)d_in[2];
    const float* wv = (const float*)d_in[3];
    const float* wo = (const float*)d_in[4];
    float* out = (float*)d_out;

    // ws layout (88MB, with time-sliced aliasing):
    //   wT slot 32MB: wqT -> wkT -> wvT -> ao (flash output)
    //   q  slot 32MB: q -> woT
    //   k 8 | v 8 | vt 8
    f16* wT = (f16*)d_ws;                              // [4096][4096] max
    f16* q  = wT + (size_t)HIDSZ * HIDSZ;              // [4096][4096]
    f16* k  = q  + (size_t)MROWS * HIDSZ;              // [4096][1024]
    f16* v  = k  + (size_t)MROWS * KVDIM;              // [4096][1024]
    f16* vt = v  + (size_t)MROWS * KVDIM;              // [2][8][128][2048]
    f16* ao  = wT;                                     // alias (wvT dead)
    f16* woT = q;                                      // alias (q dead)

    wtrans_kernel<<<dim3(HIDSZ / 32, HIDSZ / 32), 256, 0, stream>>>(wq, wT, HIDSZ, HIDSZ);
    gemm_bt<float, f16><<<dim3(HIDSZ / 128, MROWS / 128), 256, 0, stream>>>(
        x, wT, q, MROWS, HIDSZ, HIDSZ);

    wtrans_kernel<<<dim3(KVDIM / 32, HIDSZ / 32), 256, 0, stream>>>(wk, wT, HIDSZ, KVDIM);
    gemm_bt<float, f16><<<dim3(KVDIM / 128, MROWS / 128), 256, 0, stream>>>(
        x, wT, k, MROWS, KVDIM, HIDSZ);

    wtrans_kernel<<<dim3(KVDIM / 32, HIDSZ / 32), 256, 0, stream>>>(wv, wT, HIDSZ, KVDIM);
    gemm_bt<float, f16><<<dim3(KVDIM / 128, MROWS / 128), 256, 0, stream>>>(
        x, wT, v, MROWS, KVDIM, HIDSZ);

    rope_kernel<f16><<<(MROWS * NH * HALFD) / 256, 256, 0, stream>>>(q, NH);
    rope_kernel<f16><<<(MROWS * NKV * HALFD) / 256, 256, 0, stream>>>(k, NKV);

    transpose_v_kernel<<<dim3(SEQ / 32, HD / 32, BATCH * NKV), 256, 0, stream>>>(v, vt);

    flash_attn_kernel<<<dim3(SEQ / 128, NH, BATCH), 256, 0, stream>>>(q, k, vt, ao);

    wtrans_kernel<<<dim3(HIDSZ / 32, HIDSZ / 32), 256, 0, stream>>>(wo, woT, HIDSZ, HIDSZ);
    gemm_bt<f16, float><<<dim3(HIDSZ / 128, MROWS / 128), 256, 0, stream>>>(
        ao, woT, out, MROWS, HIDSZ, HIDSZ);
}